// Round 1
// baseline (82.190 us; speedup 1.0000x reference)
//
#include <hip/hip_runtime.h>
#include <hip/hip_bf16.h>

// SimLoss: loss = (1/n) [ sum_r log(1 + sum_{j!=r} exp(cos(r,j))) - 2*sum_m cos(m, m+4096) ]
// n=8192, d=256. Row reorder in the reference is a permutation -> den sum invariant.
// Pre-normalize rows -> Gram of normalized bf16 rows gives cosines directly.
// Workspace layout (needs ~6.05 MB):
//   xn    : u16 [8192*256]  @ 0         (4,194,304 B)  normalized bf16 rows
//   norms : f32 [8192]      @ 4,194,304 (32 KB)
//   dots  : f32 [4096]      @ 4,227,072 (16 KB)        exact fp32 pair dots
//   part  : f32 [64*8192]   @ 4,243,456 (2 MB)         per-colblock row partial exp-sums
//   bsum  : f32 [32]        @ 6,340,608

#define N_ROWS 8192
#define HALF   4096
#define DDIM   256
#define EPS    1e-6f

typedef unsigned int   u32;
typedef unsigned short u16;
typedef __attribute__((ext_vector_type(4))) float f32x4;
typedef __attribute__((ext_vector_type(8))) short bf16x8;

__device__ __forceinline__ u16 f2bf(float f) {
    u32 u = __builtin_bit_cast(u32, f);
    u32 r = u + 0x7FFFu + ((u >> 16) & 1u);   // round-to-nearest-even
    return (u16)(r >> 16);
}

// Kernel 1: row norms (fp32 exact) + normalized bf16 matrix. 1 wave per row.
__global__ __launch_bounds__(256) void prep_kernel(const float* __restrict__ x,
                                                   u16* __restrict__ xn,
                                                   float* __restrict__ norms) {
    const int w = threadIdx.x >> 6, l = threadIdx.x & 63;
    const int row = blockIdx.x * 4 + w;
    const float4 v = reinterpret_cast<const float4*>(x + (size_t)row * DDIM)[l];
    float sq = v.x * v.x + v.y * v.y + v.z * v.z + v.w * v.w;
#pragma unroll
    for (int off = 1; off < 64; off <<= 1) sq += __shfl_xor(sq, off);
    const float norm = sqrtf(sq);
    if (l == 0) norms[row] = norm;
    const float rn = 1.0f / norm;
    ushort4 o;
    o.x = f2bf(v.x * rn); o.y = f2bf(v.y * rn);
    o.z = f2bf(v.z * rn); o.w = f2bf(v.w * rn);
    reinterpret_cast<ushort4*>(xn + (size_t)row * DDIM)[l] = o;
}

// Kernel 2: exact fp32 dot(x_m, x_{m+4096}) for the numerator. 1 wave per pair.
__global__ __launch_bounds__(256) void dots_kernel(const float* __restrict__ x,
                                                   float* __restrict__ dots) {
    const int w = threadIdx.x >> 6, l = threadIdx.x & 63;
    const int m = blockIdx.x * 4 + w;
    const float4 a = reinterpret_cast<const float4*>(x + (size_t)m * DDIM)[l];
    const float4 b = reinterpret_cast<const float4*>(x + (size_t)(m + HALF) * DDIM)[l];
    float s = a.x * b.x + a.y * b.y + a.z * b.z + a.w * b.w;
#pragma unroll
    for (int off = 1; off < 64; off <<= 1) s += __shfl_xor(s, off);
    if (l == 0) dots[m] = s;
}

// Kernel 3: fused Gram(exp-rowsum). 128x128 tile per block, 4 waves (2x2 of 64x64),
// BK=64, global_load_lds width 16, MFMA 16x16x32 bf16. Epilogue: exp + row-reduce,
// deterministic partials part[bj][row].
__global__ __launch_bounds__(256) void gram_kernel(const u16* __restrict__ xn,
                                                   float* __restrict__ part) {
    const int bi = blockIdx.x, bj = blockIdx.y;
    const int r0 = bi * 128, c0 = bj * 128;
    __shared__ __align__(16) u16 As[128 * 64];
    __shared__ __align__(16) u16 Bs[128 * 64];
    __shared__ float dsh[2][128];

    const int tid = threadIdx.x;
    const int w = tid >> 6, l = tid & 63;
    const int wr = w >> 1, wc = w & 1;

    const f32x4 vzero = {0.f, 0.f, 0.f, 0.f};
    f32x4 acc[4][4];
#pragma unroll
    for (int m = 0; m < 4; ++m)
#pragma unroll
        for (int n = 0; n < 4; ++n) acc[m][n] = vzero;

    const int krow = l >> 3;        // 0..7 row within 8-row staging chunk
    const int kcol = (l & 7) * 8;   // 0..56 element col within 64-wide K slice

    for (int ks = 0; ks < 4; ++ks) {
#pragma unroll
        for (int i = 0; i < 4; ++i) {
            const int rr = w * 32 + i * 8;  // wave-uniform LDS row base
            const u16* ga = xn + (size_t)(r0 + rr + krow) * DDIM + ks * 64 + kcol;
            __builtin_amdgcn_global_load_lds(
                (const __attribute__((address_space(1))) u32*)ga,
                (__attribute__((address_space(3))) u32*)(As + rr * 64), 16, 0, 0);
            const u16* gb = xn + (size_t)(c0 + rr + krow) * DDIM + ks * 64 + kcol;
            __builtin_amdgcn_global_load_lds(
                (const __attribute__((address_space(1))) u32*)gb,
                (__attribute__((address_space(3))) u32*)(Bs + rr * 64), 16, 0, 0);
        }
        __syncthreads();
#pragma unroll
        for (int s = 0; s < 2; ++s) {
            bf16x8 a[4], b[4];
            const int koff = s * 32 + (l >> 4) * 8;
#pragma unroll
            for (int m = 0; m < 4; ++m)
                a[m] = *reinterpret_cast<const bf16x8*>(As + (wr * 64 + m * 16 + (l & 15)) * 64 + koff);
#pragma unroll
            for (int n = 0; n < 4; ++n)
                b[n] = *reinterpret_cast<const bf16x8*>(Bs + (wc * 64 + n * 16 + (l & 15)) * 64 + koff);
#pragma unroll
            for (int m = 0; m < 4; ++m)
#pragma unroll
                for (int n = 0; n < 4; ++n)
                    acc[m][n] = __builtin_amdgcn_mfma_f32_16x16x32_bf16(a[m], b[n], acc[m][n], 0, 0, 0);
        }
        __syncthreads();
    }

    // Epilogue: e = (diag ? 1 : exp(cos)); row-sum across 16-lane col groups.
    // C/D layout: col = lane&15, row = (lane>>4)*4 + reg  [verified m89/m91]
    const int rbase = r0 + wr * 64 + (l >> 4) * 4;
    const int cbase = c0 + wc * 64 + (l & 15);
#pragma unroll
    for (int m = 0; m < 4; ++m) {
#pragma unroll
        for (int rg = 0; rg < 4; ++rg) {
            const int grow = rbase + m * 16 + rg;
            float rs = 0.f;
#pragma unroll
            for (int n = 0; n < 4; ++n) {
                const int gcol = cbase + n * 16;
                const float cosv = acc[m][n][rg];
                rs += (grow == gcol) ? 1.0f : __expf(cosv);
            }
            rs += __shfl_xor(rs, 1);
            rs += __shfl_xor(rs, 2);
            rs += __shfl_xor(rs, 4);
            rs += __shfl_xor(rs, 8);
            if ((l & 15) == 0)
                dsh[wc][wr * 64 + m * 16 + (l >> 4) * 4 + rg] = rs;
        }
    }
    __syncthreads();
    if (tid < 128)
        part[(size_t)bj * N_ROWS + r0 + tid] = dsh[0][tid] + dsh[1][tid];
}

// Kernel 4: den_r = sum_bj part[bj][r]; local = log(den_r) - 2*num (first 128 lanes);
// block-reduce -> bsum[b].
__global__ __launch_bounds__(256) void fin1_kernel(const float* __restrict__ part,
                                                   const float* __restrict__ norms,
                                                   const float* __restrict__ dots,
                                                   float* __restrict__ bsum) {
    const int b = blockIdx.x, t = threadIdx.x;
    const int r = b * 256 + t;
    float den = 0.f;
#pragma unroll 8
    for (int bj = 0; bj < 64; ++bj) den += part[(size_t)bj * N_ROWS + r];
    float local = logf(den);
    if (t < 128) {
        const int m = b * 128 + t;
        local -= 2.0f * dots[m] / (norms[m] * norms[m + HALF]);
    }
#pragma unroll
    for (int off = 1; off < 64; off <<= 1) local += __shfl_xor(local, off);
    __shared__ float wsum[4];
    if ((t & 63) == 0) wsum[t >> 6] = local;
    __syncthreads();
    if (t == 0) bsum[b] = wsum[0] + wsum[1] + wsum[2] + wsum[3];
}

__global__ void fin2_kernel(const float* __restrict__ bsum, float* __restrict__ out) {
    const int t = threadIdx.x;
    float v = (t < 32) ? bsum[t] : 0.f;
#pragma unroll
    for (int off = 1; off < 32; off <<= 1) v += __shfl_xor(v, off);
    if (t == 0) out[0] = v / (float)N_ROWS;
}

extern "C" void kernel_launch(void* const* d_in, const int* in_sizes, int n_in,
                              void* d_out, int out_size, void* d_ws, size_t ws_size,
                              hipStream_t stream) {
    const float* x = (const float*)d_in[0];
    float* out = (float*)d_out;
    char* ws = (char*)d_ws;

    u16*   xn    = (u16*)ws;
    float* norms = (float*)(ws + 4194304);
    float* dots  = (float*)(ws + 4227072);
    float* part  = (float*)(ws + 4243456);
    float* bsum  = (float*)(ws + 6340608);

    prep_kernel<<<2048, 256, 0, stream>>>(x, xn, norms);
    dots_kernel<<<1024, 256, 0, stream>>>(x, dots);
    gram_kernel<<<dim3(64, 64), 256, 0, stream>>>(xn, part);
    fin1_kernel<<<32, 256, 0, stream>>>(part, norms, dots, bsum);
    fin2_kernel<<<1, 64, 0, stream>>>(bsum, out);
}

// Round 2
// 45.729 us; speedup vs baseline: 1.7973x; 1.7973x over previous
//
#include <hip/hip_runtime.h>
#include <hip/hip_bf16.h>

// SimLoss: loss = (1/n) [ sum_r log(1 + sum_{j!=r} exp(cos(r,j))) - 2*sum_m cos(m, m+4096) ]
// n=8192, d=256. Row reorder is a permutation -> den sum invariant.
// R2: symmetric Gram (upper-triangle blocks only, row+col sums) + swapped-operand
// epilogue (row-sum lane-local: 2 shuffles instead of 64) + LDS col-sum reduce.
// Workspace layout (~6.05 MB):
//   xn    : u16 [8192*256]  @ 0         (4,194,304 B)  normalized bf16 rows
//   norms : f32 [8192]      @ 4,194,304 (32 KB)
//   dots  : f32 [4096]      @ 4,227,072 (16 KB)        exact fp32 pair dots
//   part  : f32 [64*8192]   @ 4,243,456 (2 MB)         per-colblock row partial exp-sums
//   bsum  : f32 [32]        @ 6,340,608

#define N_ROWS 8192
#define HALF   4096
#define DDIM   256
#define NBLK   64          // 8192/128 row panels

typedef unsigned int   u32;
typedef unsigned short u16;
typedef __attribute__((ext_vector_type(4))) float f32x4;
typedef __attribute__((ext_vector_type(8))) short bf16x8;

__device__ __forceinline__ u16 f2bf(float f) {
    u32 u = __builtin_bit_cast(u32, f);
    u32 r = u + 0x7FFFu + ((u >> 16) & 1u);   // round-to-nearest-even
    return (u16)(r >> 16);
}

// Kernel 1 (merged): blocks [0,2048): row norms + normalized bf16 matrix (1 wave/row).
//                    blocks [2048,3072): exact fp32 dot(x_m, x_{m+4096}) (1 wave/pair).
__global__ __launch_bounds__(256) void prep_kernel(const float* __restrict__ x,
                                                   u16* __restrict__ xn,
                                                   float* __restrict__ norms,
                                                   float* __restrict__ dots) {
    const int w = threadIdx.x >> 6, l = threadIdx.x & 63;
    if (blockIdx.x < 2048) {
        const int row = blockIdx.x * 4 + w;
        const float4 v = reinterpret_cast<const float4*>(x + (size_t)row * DDIM)[l];
        float sq = v.x * v.x + v.y * v.y + v.z * v.z + v.w * v.w;
#pragma unroll
        for (int off = 1; off < 64; off <<= 1) sq += __shfl_xor(sq, off);
        const float norm = sqrtf(sq);
        if (l == 0) norms[row] = norm;
        const float rn = 1.0f / norm;
        ushort4 o;
        o.x = f2bf(v.x * rn); o.y = f2bf(v.y * rn);
        o.z = f2bf(v.z * rn); o.w = f2bf(v.w * rn);
        reinterpret_cast<ushort4*>(xn + (size_t)row * DDIM)[l] = o;
    } else {
        const int m = (blockIdx.x - 2048) * 4 + w;
        const float4 a = reinterpret_cast<const float4*>(x + (size_t)m * DDIM)[l];
        const float4 b = reinterpret_cast<const float4*>(x + (size_t)(m + HALF) * DDIM)[l];
        float s = a.x * b.x + a.y * b.y + a.z * b.z + a.w * b.w;
#pragma unroll
        for (int off = 1; off < 64; off <<= 1) s += __shfl_xor(s, off);
        if (l == 0) dots[m] = s;
    }
}

// Kernel 2: symmetric fused Gram(exp row+col sums). Upper-triangle 128x128 tiles,
// 4 waves (2x2 of 64x64), BK=64, global_load_lds w16, MFMA 16x16x32 bf16 SWAPPED:
// acc[m][n] = mfma(b[m], a[n], .) -> D col (lane&15) = global row r, D row = col j.
// part[bj][r in bi-panel] = rowsum ; part[bi][c in bj-panel] = colsum (off-diag).
__global__ __launch_bounds__(256) void gram_kernel(const u16* __restrict__ xn,
                                                   float* __restrict__ part) {
    // triangular decode: blockIdx.x -> (bi, bj), bi <= bj
    int t = blockIdx.x, bi = 0;
    while (t >= NBLK - bi) { t -= NBLK - bi; ++bi; }
    const int bj = bi + t;
    const bool diagblk = (bi == bj);
    const int r0 = bi * 128, c0 = bj * 128;

    __shared__ __align__(16) char smem[32768];
    u16* As = (u16*)smem;             // [128][64]
    u16* Bs = (u16*)(smem + 16384);   // [128][64]

    const int tid = threadIdx.x;
    const int w = tid >> 6, l = tid & 63;
    const int wr = w >> 1, wc = w & 1;

    const f32x4 vzero = {0.f, 0.f, 0.f, 0.f};
    f32x4 acc[4][4];
#pragma unroll
    for (int m = 0; m < 4; ++m)
#pragma unroll
        for (int n = 0; n < 4; ++n) acc[m][n] = vzero;

    const int krow = l >> 3;        // 0..7 row within 8-row staging chunk
    const int kcol = (l & 7) * 8;   // 0..56 element col within 64-wide K slice

    for (int ks = 0; ks < 4; ++ks) {
#pragma unroll
        for (int i = 0; i < 4; ++i) {
            const int rr = w * 32 + i * 8;  // wave-uniform LDS row base
            const u16* ga = xn + (size_t)(r0 + rr + krow) * DDIM + ks * 64 + kcol;
            __builtin_amdgcn_global_load_lds(
                (const __attribute__((address_space(1))) u32*)ga,
                (__attribute__((address_space(3))) u32*)(As + rr * 64), 16, 0, 0);
            const u16* gb = xn + (size_t)(c0 + rr + krow) * DDIM + ks * 64 + kcol;
            __builtin_amdgcn_global_load_lds(
                (const __attribute__((address_space(1))) u32*)gb,
                (__attribute__((address_space(3))) u32*)(Bs + rr * 64), 16, 0, 0);
        }
        __syncthreads();
#pragma unroll
        for (int s = 0; s < 2; ++s) {
            bf16x8 a[4], b[4];
            const int koff = s * 32 + (l >> 4) * 8;
#pragma unroll
            for (int n = 0; n < 4; ++n)
                a[n] = *reinterpret_cast<const bf16x8*>(As + (wr * 64 + n * 16 + (l & 15)) * 64 + koff);
#pragma unroll
            for (int m = 0; m < 4; ++m)
                b[m] = *reinterpret_cast<const bf16x8*>(Bs + (wc * 64 + m * 16 + (l & 15)) * 64 + koff);
            // swapped operands: D row <- B rows (cols j), D col <- A rows (rows r)
#pragma unroll
            for (int m = 0; m < 4; ++m)
#pragma unroll
                for (int n = 0; n < 4; ++n)
                    acc[m][n] = __builtin_amdgcn_mfma_f32_16x16x32_bf16(b[m], a[n], acc[m][n], 0, 0, 0);
        }
        __syncthreads();  // last one also fences LDS reuse below
    }

    // Layout (swapped): r = r0 + wr*64 + n*16 + (l&15); j = c0 + wc*64 + m*16 + (l>>4)*4 + rg
    // exp in place (diag -> 1.0)
#pragma unroll
    for (int m = 0; m < 4; ++m)
#pragma unroll
        for (int n = 0; n < 4; ++n)
#pragma unroll
            for (int rg = 0; rg < 4; ++rg) {
                const float e = __expf(acc[m][n][rg]);
                if (diagblk) {
                    const int j_loc = wc * 64 + m * 16 + (l >> 4) * 4 + rg;
                    const int r_loc = wr * 64 + n * 16 + (l & 15);
                    acc[m][n][rg] = (j_loc == r_loc) ? 1.0f : e;
                } else {
                    acc[m][n][rg] = e;
                }
            }

    // LDS scratch reuse (post-barrier): cs [2 wr][128 j][17 pad], dsh [2 wc][128 r]
    float* cs  = (float*)smem;               // 2*128*17*4 = 17408 B
    float* dsh = (float*)(smem + 24576);     // 2*128*4   =  1024 B

    // row-sums (den): lane-local over m,rg; 2 shuffles across l>>4 groups
#pragma unroll
    for (int n = 0; n < 4; ++n) {
        float s = 0.f;
#pragma unroll
        for (int m = 0; m < 4; ++m)
#pragma unroll
            for (int rg = 0; rg < 4; ++rg) s += acc[m][n][rg];
        s += __shfl_xor(s, 16);
        s += __shfl_xor(s, 32);
        if (l < 16) dsh[wc * 128 + wr * 64 + n * 16 + l] = s;
    }

    // col-sums (off-diag only): per-lane partial over n, staged to LDS
    if (!diagblk) {
#pragma unroll
        for (int m = 0; m < 4; ++m)
#pragma unroll
            for (int rg = 0; rg < 4; ++rg) {
                const float s = acc[m][0][rg] + acc[m][1][rg] + acc[m][2][rg] + acc[m][3][rg];
                const int j_loc = wc * 64 + m * 16 + (l >> 4) * 4 + rg;
                cs[(wr * 128 + j_loc) * 17 + (l & 15)] = s;
            }
    }
    __syncthreads();

    if (tid < 128) {
        const float den = dsh[tid] + dsh[128 + tid];
        part[(size_t)bj * N_ROWS + r0 + tid] = den;
        if (!diagblk) {
            float c = 0.f;
#pragma unroll
            for (int k = 0; k < 16; ++k)
                c += cs[tid * 17 + k] + cs[(128 + tid) * 17 + k];
            part[(size_t)bi * N_ROWS + c0 + tid] = c;
        }
    }
}

// Kernel 3: den_r = sum_bj part[bj][r]; local = log(den_r) - 2*num (first 128 lanes);
// block-reduce -> bsum[b].
__global__ __launch_bounds__(256) void fin1_kernel(const float* __restrict__ part,
                                                   const float* __restrict__ norms,
                                                   const float* __restrict__ dots,
                                                   float* __restrict__ bsum) {
    const int b = blockIdx.x, t = threadIdx.x;
    const int r = b * 256 + t;
    float den = 0.f;
#pragma unroll 8
    for (int bj = 0; bj < 64; ++bj) den += part[(size_t)bj * N_ROWS + r];
    float local = logf(den);
    if (t < 128) {
        const int m = b * 128 + t;
        local -= 2.0f * dots[m] / (norms[m] * norms[m + HALF]);
    }
#pragma unroll
    for (int off = 1; off < 64; off <<= 1) local += __shfl_xor(local, off);
    __shared__ float wsum[4];
    if ((t & 63) == 0) wsum[t >> 6] = local;
    __syncthreads();
    if (t == 0) bsum[b] = wsum[0] + wsum[1] + wsum[2] + wsum[3];
}

__global__ void fin2_kernel(const float* __restrict__ bsum, float* __restrict__ out) {
    const int t = threadIdx.x;
    float v = (t < 32) ? bsum[t] : 0.f;
#pragma unroll
    for (int off = 1; off < 32; off <<= 1) v += __shfl_xor(v, off);
    if (t == 0) out[0] = v / (float)N_ROWS;
}

extern "C" void kernel_launch(void* const* d_in, const int* in_sizes, int n_in,
                              void* d_out, int out_size, void* d_ws, size_t ws_size,
                              hipStream_t stream) {
    const float* x = (const float*)d_in[0];
    float* out = (float*)d_out;
    char* ws = (char*)d_ws;

    u16*   xn    = (u16*)ws;
    float* norms = (float*)(ws + 4194304);
    float* dots  = (float*)(ws + 4227072);
    float* part  = (float*)(ws + 4243456);
    float* bsum  = (float*)(ws + 6340608);

    prep_kernel<<<3072, 256, 0, stream>>>(x, xn, norms, dots);
    gram_kernel<<<(NBLK * (NBLK + 1)) / 2, 256, 0, stream>>>(xn, part);
    fin1_kernel<<<32, 256, 0, stream>>>(part, norms, dots, bsum);
    fin2_kernel<<<1, 64, 0, stream>>>(bsum, out);
}

// Round 3
// 41.685 us; speedup vs baseline: 1.9717x; 1.0970x over previous
//
#include <hip/hip_runtime.h>
#include <hip/hip_bf16.h>

// SimLoss: loss = (1/n) [ sum_r log(1 + sum_{j!=r} exp(cos(r,j))) - 2*sum_m cos(m, m+4096) ]
// n=8192, d=256. Row reorder is a permutation -> den sum invariant.
// R3: + LDS XOR-swizzle via pre-swizzled global source (rule #21: linear dest +
//     inverse-swz source + swz on read). Granule (16B) index g ^= (row&7).
//     Fixes the 16-way bank conflict of the [128][64] bf16 tile (row stride 128B).
// Workspace layout (~6.05 MB):
//   xn    : u16 [8192*256]  @ 0         (4,194,304 B)  normalized bf16 rows
//   norms : f32 [8192]      @ 4,194,304 (32 KB)
//   dots  : f32 [4096]      @ 4,227,072 (16 KB)        exact fp32 pair dots
//   part  : f32 [64*8192]   @ 4,243,456 (2 MB)         per-colblock row partial exp-sums
//   bsum  : f32 [32]        @ 6,340,608

#define N_ROWS 8192
#define HALF   4096
#define DDIM   256
#define NBLK   64          // 8192/128 row panels

typedef unsigned int   u32;
typedef unsigned short u16;
typedef __attribute__((ext_vector_type(4))) float f32x4;
typedef __attribute__((ext_vector_type(8))) short bf16x8;

__device__ __forceinline__ u16 f2bf(float f) {
    u32 u = __builtin_bit_cast(u32, f);
    u32 r = u + 0x7FFFu + ((u >> 16) & 1u);   // round-to-nearest-even
    return (u16)(r >> 16);
}

// Kernel 1 (merged): blocks [0,2048): row norms + normalized bf16 matrix (1 wave/row).
//                    blocks [2048,3072): exact fp32 dot(x_m, x_{m+4096}) (1 wave/pair).
__global__ __launch_bounds__(256) void prep_kernel(const float* __restrict__ x,
                                                   u16* __restrict__ xn,
                                                   float* __restrict__ norms,
                                                   float* __restrict__ dots) {
    const int w = threadIdx.x >> 6, l = threadIdx.x & 63;
    if (blockIdx.x < 2048) {
        const int row = blockIdx.x * 4 + w;
        const float4 v = reinterpret_cast<const float4*>(x + (size_t)row * DDIM)[l];
        float sq = v.x * v.x + v.y * v.y + v.z * v.z + v.w * v.w;
#pragma unroll
        for (int off = 1; off < 64; off <<= 1) sq += __shfl_xor(sq, off);
        const float norm = sqrtf(sq);
        if (l == 0) norms[row] = norm;
        const float rn = 1.0f / norm;
        ushort4 o;
        o.x = f2bf(v.x * rn); o.y = f2bf(v.y * rn);
        o.z = f2bf(v.z * rn); o.w = f2bf(v.w * rn);
        reinterpret_cast<ushort4*>(xn + (size_t)row * DDIM)[l] = o;
    } else {
        const int m = (blockIdx.x - 2048) * 4 + w;
        const float4 a = reinterpret_cast<const float4*>(x + (size_t)m * DDIM)[l];
        const float4 b = reinterpret_cast<const float4*>(x + (size_t)(m + HALF) * DDIM)[l];
        float s = a.x * b.x + a.y * b.y + a.z * b.z + a.w * b.w;
#pragma unroll
        for (int off = 1; off < 64; off <<= 1) s += __shfl_xor(s, off);
        if (l == 0) dots[m] = s;
    }
}

// Kernel 2: symmetric fused Gram(exp row+col sums). Upper-triangle 128x128 tiles,
// 4 waves (2x2 of 64x64), BK=64, global_load_lds w16 (swizzled source), MFMA
// 16x16x32 bf16 SWAPPED: acc[m][n] = mfma(b[m], a[n], .) -> D col (lane&15) = row r.
// part[bj][r in bi-panel] = rowsum ; part[bi][c in bj-panel] = colsum (off-diag).
__global__ __launch_bounds__(256) void gram_kernel(const u16* __restrict__ xn,
                                                   float* __restrict__ part) {
    // triangular decode: blockIdx.x -> (bi, bj), bi <= bj. off(b) = b*(129-b)/2.
    const int t = blockIdx.x;
    int bi = (int)(0.5f * (129.0f - sqrtf(16641.0f - 8.0f * (float)t)));
    if (bi > 0 && bi * (129 - bi) / 2 > t) --bi;                     // fixup down
    if ((bi + 1) * (129 - (bi + 1)) / 2 <= t) ++bi;                  // fixup up
    const int bj = bi + (t - bi * (129 - bi) / 2);
    const bool diagblk = (bi == bj);
    const int r0 = bi * 128, c0 = bj * 128;

    __shared__ __align__(16) char smem[32768];
    u16* As = (u16*)smem;             // [128][64] (granule-swizzled within rows)
    u16* Bs = (u16*)(smem + 16384);   // [128][64]

    const int tid = threadIdx.x;
    const int w = tid >> 6, l = tid & 63;
    const int wr = w >> 1, wc = w & 1;

    const f32x4 vzero = {0.f, 0.f, 0.f, 0.f};
    f32x4 acc[4][4];
#pragma unroll
    for (int m = 0; m < 4; ++m)
#pragma unroll
        for (int n = 0; n < 4; ++n) acc[m][n] = vzero;

    // staging: each instr covers 8 rows x 64 cols (1 KB). lane l -> row chunk+krow,
    // LDS granule l&7; SOURCE granule XOR-swizzled so LDS[row][g] = glob[row][g^(row&7)].
    const int krow = l >> 3;                         // 0..7
    const int kcol = (((l & 7) ^ krow) * 8);         // swizzled source col (elements)

    // read-side swizzle: element offset = row*64 + (koff ^ ((row&7)<<3)); row&7 == l&7
    const int rsw = (l & 7) << 3;

    for (int ks = 0; ks < 4; ++ks) {
#pragma unroll
        for (int i = 0; i < 4; ++i) {
            const int rr = w * 32 + i * 8;  // wave-uniform LDS row base
            const u16* ga = xn + (size_t)(r0 + rr + krow) * DDIM + ks * 64 + kcol;
            __builtin_amdgcn_global_load_lds(
                (const __attribute__((address_space(1))) u32*)ga,
                (__attribute__((address_space(3))) u32*)(As + rr * 64), 16, 0, 0);
            const u16* gb = xn + (size_t)(c0 + rr + krow) * DDIM + ks * 64 + kcol;
            __builtin_amdgcn_global_load_lds(
                (const __attribute__((address_space(1))) u32*)gb,
                (__attribute__((address_space(3))) u32*)(Bs + rr * 64), 16, 0, 0);
        }
        __syncthreads();
#pragma unroll
        for (int s = 0; s < 2; ++s) {
            bf16x8 a[4], b[4];
            const int koff = (s * 32 + (l >> 4) * 8) ^ rsw;
#pragma unroll
            for (int n = 0; n < 4; ++n)
                a[n] = *reinterpret_cast<const bf16x8*>(As + (wr * 64 + n * 16 + (l & 15)) * 64 + koff);
#pragma unroll
            for (int m = 0; m < 4; ++m)
                b[m] = *reinterpret_cast<const bf16x8*>(Bs + (wc * 64 + m * 16 + (l & 15)) * 64 + koff);
            // swapped operands: D row <- B rows (cols j), D col <- A rows (rows r)
#pragma unroll
            for (int m = 0; m < 4; ++m)
#pragma unroll
                for (int n = 0; n < 4; ++n)
                    acc[m][n] = __builtin_amdgcn_mfma_f32_16x16x32_bf16(b[m], a[n], acc[m][n], 0, 0, 0);
        }
        __syncthreads();  // last one also fences LDS reuse below
    }

    // Layout (swapped): r = r0 + wr*64 + n*16 + (l&15); j = c0 + wc*64 + m*16 + (l>>4)*4 + rg
    // exp in place (diag -> 1.0)
#pragma unroll
    for (int m = 0; m < 4; ++m)
#pragma unroll
        for (int n = 0; n < 4; ++n)
#pragma unroll
            for (int rg = 0; rg < 4; ++rg) {
                const float e = __expf(acc[m][n][rg]);
                if (diagblk) {
                    const int j_loc = wc * 64 + m * 16 + (l >> 4) * 4 + rg;
                    const int r_loc = wr * 64 + n * 16 + (l & 15);
                    acc[m][n][rg] = (j_loc == r_loc) ? 1.0f : e;
                } else {
                    acc[m][n][rg] = e;
                }
            }

    // LDS scratch reuse (post-barrier): cs [2 wr][128 j][17 pad], dsh [2 wc][128 r]
    float* cs  = (float*)smem;               // 2*128*17*4 = 17408 B
    float* dsh = (float*)(smem + 24576);     // 2*128*4   =  1024 B

    // row-sums (den): lane-local over m,rg; 2 shuffles across l>>4 groups
#pragma unroll
    for (int n = 0; n < 4; ++n) {
        float s = 0.f;
#pragma unroll
        for (int m = 0; m < 4; ++m)
#pragma unroll
            for (int rg = 0; rg < 4; ++rg) s += acc[m][n][rg];
        s += __shfl_xor(s, 16);
        s += __shfl_xor(s, 32);
        if (l < 16) dsh[wc * 128 + wr * 64 + n * 16 + l] = s;
    }

    // col-sums (off-diag only): per-lane partial over n, staged to LDS
    if (!diagblk) {
#pragma unroll
        for (int m = 0; m < 4; ++m)
#pragma unroll
            for (int rg = 0; rg < 4; ++rg) {
                const float s = acc[m][0][rg] + acc[m][1][rg] + acc[m][2][rg] + acc[m][3][rg];
                const int j_loc = wc * 64 + m * 16 + (l >> 4) * 4 + rg;
                cs[(wr * 128 + j_loc) * 17 + (l & 15)] = s;
            }
    }
    __syncthreads();

    if (tid < 128) {
        const float den = dsh[tid] + dsh[128 + tid];
        part[(size_t)bj * N_ROWS + r0 + tid] = den;
        if (!diagblk) {
            float c = 0.f;
#pragma unroll
            for (int k = 0; k < 16; ++k)
                c += cs[tid * 17 + k] + cs[(128 + tid) * 17 + k];
            part[(size_t)bi * N_ROWS + c0 + tid] = c;
        }
    }
}

// Kernel 3: den_r = sum_bj part[bj][r]; local = log(den_r) - 2*num (first 128 lanes);
// block-reduce -> bsum[b].
__global__ __launch_bounds__(256) void fin1_kernel(const float* __restrict__ part,
                                                   const float* __restrict__ norms,
                                                   const float* __restrict__ dots,
                                                   float* __restrict__ bsum) {
    const int b = blockIdx.x, t = threadIdx.x;
    const int r = b * 256 + t;
    float den = 0.f;
#pragma unroll 8
    for (int bj = 0; bj < 64; ++bj) den += part[(size_t)bj * N_ROWS + r];
    float local = logf(den);
    if (t < 128) {
        const int m = b * 128 + t;
        local -= 2.0f * dots[m] / (norms[m] * norms[m + HALF]);
    }
#pragma unroll
    for (int off = 1; off < 64; off <<= 1) local += __shfl_xor(local, off);
    __shared__ float wsum[4];
    if ((t & 63) == 0) wsum[t >> 6] = local;
    __syncthreads();
    if (t == 0) bsum[b] = wsum[0] + wsum[1] + wsum[2] + wsum[3];
}

__global__ void fin2_kernel(const float* __restrict__ bsum, float* __restrict__ out) {
    const int t = threadIdx.x;
    float v = (t < 32) ? bsum[t] : 0.f;
#pragma unroll
    for (int off = 1; off < 32; off <<= 1) v += __shfl_xor(v, off);
    if (t == 0) out[0] = v / (float)N_ROWS;
}

extern "C" void kernel_launch(void* const* d_in, const int* in_sizes, int n_in,
                              void* d_out, int out_size, void* d_ws, size_t ws_size,
                              hipStream_t stream) {
    const float* x = (const float*)d_in[0];
    float* out = (float*)d_out;
    char* ws = (char*)d_ws;

    u16*   xn    = (u16*)ws;
    float* norms = (float*)(ws + 4194304);
    float* dots  = (float*)(ws + 4227072);
    float* part  = (float*)(ws + 4243456);
    float* bsum  = (float*)(ws + 6340608);

    prep_kernel<<<3072, 256, 0, stream>>>(x, xn, norms, dots);
    gram_kernel<<<(NBLK * (NBLK + 1)) / 2, 256, 0, stream>>>(xn, part);
    fin1_kernel<<<32, 256, 0, stream>>>(part, norms, dots, bsum);
    fin2_kernel<<<1, 64, 0, stream>>>(bsum, out);
}

// Round 4
// 34.105 us; speedup vs baseline: 2.4099x; 1.2222x over previous
//
#include <hip/hip_runtime.h>
#include <hip/hip_bf16.h>

// SimLoss: loss = (1/n) [ sum_r log(1 + sum_{j!=r} exp(cos(r,j))) - 2*sum_m cos(m, m+4096) ]
// n=8192, d=256. R4: Gram in MX-scaled FP8 (e4m3, scale=1.0, data prescaled x16):
// mfma_scale_f32_16x16x128_f8f6f4, K=256 = 2 MFMA steps, BK=128 -> 2 staging rounds.
// Swapped operands (row-sum lane-local) + granule XOR swizzle (linear LDS dest,
// pre-swizzled source, swizzled read). Numerator exact fp32.
// Workspace (~4.25 MB):
//   xq    : u8  [8192*256]  @ 0         (2,097,152 B)  fp8 e4m3 of 16*x/||x||
//   norms : f32 [8192]      @ 2,097,152 (32 KB)
//   dots  : f32 [4096]      @ 2,129,920 (16 KB)
//   part  : f32 [64*8192]   @ 2,146,304 (2 MB)
//   bsum  : f32 [32]        @ 4,243,456

#define N_ROWS 8192
#define HALF   4096
#define DDIM   256
#define NBLK   64

typedef unsigned int   u32;
typedef unsigned char  u8;
typedef __attribute__((ext_vector_type(4))) float f32x4;
typedef __attribute__((ext_vector_type(4))) int   i32x4;
typedef __attribute__((ext_vector_type(8))) int   i32x8;

// float -> OCP e4m3fn (RNE). Assumes |f| <= 448, finite.
__device__ __forceinline__ u32 f2e4m3(float f) {
    const u32 u = __builtin_bit_cast(u32, f);
    const u32 s = (u >> 24) & 0x80u;
    const float af = fabsf(f);
    if (af < 0.015625f) {                        // subnormal: step 2^-9 (mi=8 -> 0x08 = 2^-6)
        const int mi = (int)rintf(af * 512.0f);
        return s | (u32)mi;
    }
    u32 keep = (u & 0x7FFFFFFFu) >> 20;          // exp(8)|mant(3)
    const u32 rem = u & 0xFFFFFu;
    keep += (rem > 0x80000u) || (rem == 0x80000u && (keep & 1u));
    const int ef = (int)(keep >> 3) - 120;       // -127+7
    return s | ((u32)ef << 3) | (keep & 7u);
}

// Kernel 1: blocks [0,2048): norms + fp8 rows (prescaled x16). [2048,3072): exact pair dots.
__global__ __launch_bounds__(256) void prep_kernel(const float* __restrict__ x,
                                                   u8* __restrict__ xq,
                                                   float* __restrict__ norms,
                                                   float* __restrict__ dots) {
    const int w = threadIdx.x >> 6, l = threadIdx.x & 63;
    if (blockIdx.x < 2048) {
        const int row = blockIdx.x * 4 + w;
        const float4 v = reinterpret_cast<const float4*>(x + (size_t)row * DDIM)[l];
        float sq = v.x * v.x + v.y * v.y + v.z * v.z + v.w * v.w;
#pragma unroll
        for (int off = 1; off < 64; off <<= 1) sq += __shfl_xor(sq, off);
        const float norm = sqrtf(sq);
        if (l == 0) norms[row] = norm;
        const float rs = 16.0f / norm;
        const u32 pk = f2e4m3(v.x * rs) | (f2e4m3(v.y * rs) << 8) |
                       (f2e4m3(v.z * rs) << 16) | (f2e4m3(v.w * rs) << 24);
        reinterpret_cast<u32*>(xq + (size_t)row * DDIM)[l] = pk;
    } else {
        const int m = (blockIdx.x - 2048) * 4 + w;
        const float4 a = reinterpret_cast<const float4*>(x + (size_t)m * DDIM)[l];
        const float4 b = reinterpret_cast<const float4*>(x + (size_t)(m + HALF) * DDIM)[l];
        float s = a.x * b.x + a.y * b.y + a.z * b.z + a.w * b.w;
#pragma unroll
        for (int off = 1; off < 64; off <<= 1) s += __shfl_xor(s, off);
        if (l == 0) dots[m] = s;
    }
}

// Kernel 2: symmetric fused Gram (MX-fp8). 128x128 tile, 4 waves (2x2 of 64x64),
// BK=128 (2 rounds), mfma_scale 16x16x128 with unit scales. acc = 256*cos.
__global__ __launch_bounds__(256) void gram_kernel(const u8* __restrict__ xq,
                                                   float* __restrict__ part) {
    const int t = blockIdx.x;
    int bi = (int)(0.5f * (129.0f - sqrtf(16641.0f - 8.0f * (float)t)));
    if (bi > 0 && bi * (129 - bi) / 2 > t) --bi;
    if ((bi + 1) * (129 - (bi + 1)) / 2 <= t) ++bi;
    const int bj = bi + (t - bi * (129 - bi) / 2);
    const bool diagblk = (bi == bj);
    const int r0 = bi * 128, c0 = bj * 128;

    __shared__ __align__(16) char smem[32768];
    u8* As = (u8*)smem;             // [128 rows][128 B] granule(16B)-swizzled
    u8* Bs = (u8*)(smem + 16384);

    const int tid = threadIdx.x;
    const int w = tid >> 6, l = tid & 63;
    const int wr = w >> 1, wc = w & 1;

    const f32x4 vzero = {0.f, 0.f, 0.f, 0.f};
    f32x4 acc[4][4];
#pragma unroll
    for (int m = 0; m < 4; ++m)
#pragma unroll
        for (int n = 0; n < 4; ++n) acc[m][n] = vzero;

    // staging: 1 KB per gload_lds (8 rows x 128 B). LDS[row][g] = glob[row][g^(row&7)] (16B granules)
    const int krow = l >> 3;                       // 0..7
    const int kbyte = ((l & 7) ^ krow) * 16;       // swizzled source granule byte
    const int r7 = l & 7;                          // == row&7 for all frag reads below
    const int kq2 = (l >> 4) * 2;                  // frag K-granule base (pre-swizzle)

    for (int ks = 0; ks < 2; ++ks) {
#pragma unroll
        for (int i = 0; i < 4; ++i) {
            const int rr = w * 32 + i * 8;
            const u8* ga = xq + (size_t)(r0 + rr + krow) * DDIM + ks * 128 + kbyte;
            __builtin_amdgcn_global_load_lds(
                (const __attribute__((address_space(1))) u32*)ga,
                (__attribute__((address_space(3))) u32*)(As + rr * 128), 16, 0, 0);
            const u8* gb = xq + (size_t)(c0 + rr + krow) * DDIM + ks * 128 + kbyte;
            __builtin_amdgcn_global_load_lds(
                (const __attribute__((address_space(1))) u32*)gb,
                (__attribute__((address_space(3))) u32*)(Bs + rr * 128), 16, 0, 0);
        }
        __syncthreads();

        i32x8 bfr[4];
#pragma unroll
        for (int m = 0; m < 4; ++m) {
            const u8* rowp = Bs + (wc * 64 + m * 16 + (l & 15)) * 128;
            const i32x4 lo = *reinterpret_cast<const i32x4*>(rowp + ((kq2 ^ r7) << 4));
            const i32x4 hi = *reinterpret_cast<const i32x4*>(rowp + (((kq2 + 1) ^ r7) << 4));
            bfr[m][0] = lo[0]; bfr[m][1] = lo[1]; bfr[m][2] = lo[2]; bfr[m][3] = lo[3];
            bfr[m][4] = hi[0]; bfr[m][5] = hi[1]; bfr[m][6] = hi[2]; bfr[m][7] = hi[3];
        }
#pragma unroll
        for (int n = 0; n < 4; ++n) {
            const u8* rowp = As + (wr * 64 + n * 16 + (l & 15)) * 128;
            const i32x4 lo = *reinterpret_cast<const i32x4*>(rowp + ((kq2 ^ r7) << 4));
            const i32x4 hi = *reinterpret_cast<const i32x4*>(rowp + (((kq2 + 1) ^ r7) << 4));
            i32x8 afr;
            afr[0] = lo[0]; afr[1] = lo[1]; afr[2] = lo[2]; afr[3] = lo[3];
            afr[4] = hi[0]; afr[5] = hi[1]; afr[6] = hi[2]; afr[7] = hi[3];
            // swapped operands: D col (lane&15) = A-row r, D row axis = B-row j
#pragma unroll
            for (int m = 0; m < 4; ++m)
                acc[m][n] = __builtin_amdgcn_mfma_scale_f32_16x16x128_f8f6f4(
                    bfr[m], afr, acc[m][n], 0, 0, 0, 0x7F7F7F7F, 0, 0x7F7F7F7F);
        }
        __syncthreads();
    }

    // Layout: r = r0 + wr*64 + n*16 + (l&15); j = c0 + wc*64 + m*16 + (l>>4)*4 + rg
    // cos = acc/256; exp in place (diag -> 1.0)
#pragma unroll
    for (int m = 0; m < 4; ++m)
#pragma unroll
        for (int n = 0; n < 4; ++n)
#pragma unroll
            for (int rg = 0; rg < 4; ++rg) {
                const float e = __expf(acc[m][n][rg] * 0.00390625f);
                if (diagblk) {
                    const int j_loc = wc * 64 + m * 16 + (l >> 4) * 4 + rg;
                    const int r_loc = wr * 64 + n * 16 + (l & 15);
                    acc[m][n][rg] = (j_loc == r_loc) ? 1.0f : e;
                } else {
                    acc[m][n][rg] = e;
                }
            }

    float* cs  = (float*)smem;               // [2 wr][128 j][17 pad]
    float* dsh = (float*)(smem + 24576);     // [2 wc][128 r]

#pragma unroll
    for (int n = 0; n < 4; ++n) {
        float s = 0.f;
#pragma unroll
        for (int m = 0; m < 4; ++m)
#pragma unroll
            for (int rg = 0; rg < 4; ++rg) s += acc[m][n][rg];
        s += __shfl_xor(s, 16);
        s += __shfl_xor(s, 32);
        if (l < 16) dsh[wc * 128 + wr * 64 + n * 16 + l] = s;
    }

    if (!diagblk) {
#pragma unroll
        for (int m = 0; m < 4; ++m)
#pragma unroll
            for (int rg = 0; rg < 4; ++rg) {
                const float s = acc[m][0][rg] + acc[m][1][rg] + acc[m][2][rg] + acc[m][3][rg];
                const int j_loc = wc * 64 + m * 16 + (l >> 4) * 4 + rg;
                cs[(wr * 128 + j_loc) * 17 + (l & 15)] = s;
            }
    }
    __syncthreads();

    if (tid < 128) {
        const float den = dsh[tid] + dsh[128 + tid];
        part[(size_t)bj * N_ROWS + r0 + tid] = den;
        if (!diagblk) {
            float c = 0.f;
#pragma unroll
            for (int k = 0; k < 16; ++k)
                c += cs[tid * 17 + k] + cs[(128 + tid) * 17 + k];
            part[(size_t)bi * N_ROWS + c0 + tid] = c;
        }
    }
}

__global__ __launch_bounds__(256) void fin1_kernel(const float* __restrict__ part,
                                                   const float* __restrict__ norms,
                                                   const float* __restrict__ dots,
                                                   float* __restrict__ bsum) {
    const int b = blockIdx.x, t = threadIdx.x;
    const int r = b * 256 + t;
    float den = 0.f;
#pragma unroll 8
    for (int bj = 0; bj < 64; ++bj) den += part[(size_t)bj * N_ROWS + r];
    float local = logf(den);
    if (t < 128) {
        const int m = b * 128 + t;
        local -= 2.0f * dots[m] / (norms[m] * norms[m + HALF]);
    }
#pragma unroll
    for (int off = 1; off < 64; off <<= 1) local += __shfl_xor(local, off);
    __shared__ float wsum[4];
    if ((t & 63) == 0) wsum[t >> 6] = local;
    __syncthreads();
    if (t == 0) bsum[b] = wsum[0] + wsum[1] + wsum[2] + wsum[3];
}

__global__ void fin2_kernel(const float* __restrict__ bsum, float* __restrict__ out) {
    const int t = threadIdx.x;
    float v = (t < 32) ? bsum[t] : 0.f;
#pragma unroll
    for (int off = 1; off < 32; off <<= 1) v += __shfl_xor(v, off);
    if (t == 0) out[0] = v / (float)N_ROWS;
}

extern "C" void kernel_launch(void* const* d_in, const int* in_sizes, int n_in,
                              void* d_out, int out_size, void* d_ws, size_t ws_size,
                              hipStream_t stream) {
    const float* x = (const float*)d_in[0];
    float* out = (float*)d_out;
    char* ws = (char*)d_ws;

    u8*    xq    = (u8*)ws;
    float* norms = (float*)(ws + 2097152);
    float* dots  = (float*)(ws + 2129920);
    float* part  = (float*)(ws + 2146304);
    float* bsum  = (float*)(ws + 4243456);

    prep_kernel<<<3072, 256, 0, stream>>>(x, xq, norms, dots);
    gram_kernel<<<(NBLK * (NBLK + 1)) / 2, 256, 0, stream>>>(xq, part);
    fin1_kernel<<<32, 256, 0, stream>>>(part, norms, dots, bsum);
    fin2_kernel<<<1, 64, 0, stream>>>(bsum, out);
}